// Round 1
// baseline (217.448 us; speedup 1.0000x reference)
//
#include <hip/hip_runtime.h>
#include <hip/hip_bf16.h>

#define GLOBAL_AS __attribute__((address_space(1)))
#define LDS_AS    __attribute__((address_space(3)))

typedef __bf16 bf16x8 __attribute__((ext_vector_type(8)));
typedef float  f32x4  __attribute__((ext_vector_type(4)));

constexpr int BATCH = 8192;           // M
constexpr int IN    = 1024;
constexpr int OUT   = 1024;           // N
constexpr int ORDER = 4;
constexpr int KDIM  = IN * ORDER;     // 4096
constexpr int TM = 128, TN = 128, BK = 32;

// round-to-nearest-even float -> bf16 bits (inputs are finite; no NaN path needed)
__device__ __forceinline__ unsigned short f2bf(float f) {
    union { float f; unsigned u; } v; v.f = f;
    unsigned r = v.u + 0x7fffu + ((v.u >> 16) & 1u);
    return (unsigned short)(r >> 16);
}

__device__ __forceinline__ unsigned pk(unsigned short a, unsigned short b) {
    return (unsigned)a | ((unsigned)b << 16);
}

// Build A_big[b, 4i+k] = {silu(x), x, x^2, x^3} as bf16. One thread per float4 of x.
__global__ void prep_a(const float* __restrict__ x, unsigned short* __restrict__ A) {
    int idx = blockIdx.x * 256 + threadIdx.x;          // exactly 8192*1024/4 threads
    float4 v = reinterpret_cast<const float4*>(x)[idx];
    float e0[4] = {v.x, v.y, v.z, v.w};
    unsigned short o[16];
#pragma unroll
    for (int j = 0; j < 4; ++j) {
        float xv = e0[j];
        float s  = xv / (1.0f + __expf(-xv));          // silu
        float x2 = xv * xv;
        o[4*j+0] = f2bf(s);
        o[4*j+1] = f2bf(xv);
        o[4*j+2] = f2bf(x2);
        o[4*j+3] = f2bf(x2 * xv);
    }
    uint4 d0 = make_uint4(pk(o[0],o[1]),  pk(o[2],o[3]),  pk(o[4],o[5]),  pk(o[6],o[7]));
    uint4 d1 = make_uint4(pk(o[8],o[9]),  pk(o[10],o[11]), pk(o[12],o[13]), pk(o[14],o[15]));
    uint4* dst = reinterpret_cast<uint4*>(A) + (size_t)idx * 2;
    dst[0] = d0;
    dst[1] = d1;
}

// Build B_big[o, 4i+k] = {W[o,i], C[o,i,1], C[o,i,2], C[o,i,3]}. One thread per (o,i).
__global__ void prep_b(const float* __restrict__ W, const float* __restrict__ C,
                       unsigned short* __restrict__ B) {
    int idx = blockIdx.x * 256 + threadIdx.x;          // exactly 1024*1024 threads
    float4 c = reinterpret_cast<const float4*>(C)[idx];  // C[o,i,0..3]
    float  w = W[idx];
    unsigned short o0 = f2bf(w), o1 = f2bf(c.y), o2 = f2bf(c.z), o3 = f2bf(c.w);
    reinterpret_cast<uint2*>(B)[idx] = make_uint2(pk(o0, o1), pk(o2, o3));
}

// bias_eff[o] = bias[o] + sum_i C[o,i,0]   (the x^0 Taylor term, exact fp32)
__global__ void prep_bias(const float* __restrict__ C, const float* __restrict__ bias,
                          float* __restrict__ be) {
    int o = blockIdx.x, t = threadIdx.x;
    float s = 0.f;
    for (int i = t; i < IN; i += 256) s += C[((size_t)o * IN + i) * 4];
#pragma unroll
    for (int off = 32; off > 0; off >>= 1) s += __shfl_down(s, off, 64);
    __shared__ float red[4];
    if ((t & 63) == 0) red[t >> 6] = s;
    __syncthreads();
    if (t == 0) be[o] = bias[o] + red[0] + red[1] + red[2] + red[3];
}

// C = A_big(8192x4096) * B_big(1024x4096)^T + bias_eff, bf16 MFMA, m97 structure.
__global__ __launch_bounds__(256) void gemm_kan(
        const unsigned short* __restrict__ Ab,
        const unsigned short* __restrict__ Bb,
        const float* __restrict__ be,
        float* __restrict__ out) {
    __shared__ unsigned short sA[TM * BK];   // 8 KB
    __shared__ unsigned short sB[TN * BK];   // 8 KB

    const int t    = threadIdx.x;
    const int bn   = blockIdx.x;             // 0..7
    const int bm   = blockIdx.y;             // 0..63
    const int lane = t & 63;
    const int wave = t >> 6;                 // 4 waves
    const int wr   = wave >> 1;              // wave row (0..1) -> 64 rows each
    const int wc   = wave & 1;               // wave col (0..1) -> 64 cols each
    const int l15  = lane & 15;
    const int quad = lane >> 4;              // 0..3

    // staging mapping: thread t loads 8 bf16 at (row = t>>2, k = (t&3)*8)
    const int rowS = t >> 2;
    const int colS = (t & 3) * 8;

    const unsigned short* pa0 = Ab + (size_t)(bm * TM + rowS) * KDIM + colS;
    const unsigned short* pa1 = pa0 + (size_t)64 * KDIM;
    const unsigned short* pb0 = Bb + (size_t)(bn * TN + rowS) * KDIM + colS;
    const unsigned short* pb1 = pb0 + (size_t)64 * KDIM;

    f32x4 acc[4][4];
    const f32x4 zero = {0.f, 0.f, 0.f, 0.f};
#pragma unroll
    for (int i = 0; i < 4; ++i)
#pragma unroll
        for (int j = 0; j < 4; ++j) acc[i][j] = zero;

    const int aoff = (wr * 64 + l15) * BK + quad * 8;   // + mi*16*BK
    const int boff = (wc * 64 + l15) * BK + quad * 8;   // + ni*16*BK

    for (int k0 = 0; k0 < KDIM; k0 += BK) {
        __syncthreads();
        __builtin_amdgcn_global_load_lds((const GLOBAL_AS void*)(pa0 + k0),
                                         (LDS_AS void*)(sA + t * 8), 16, 0, 0);
        __builtin_amdgcn_global_load_lds((const GLOBAL_AS void*)(pa1 + k0),
                                         (LDS_AS void*)(sA + 2048 + t * 8), 16, 0, 0);
        __builtin_amdgcn_global_load_lds((const GLOBAL_AS void*)(pb0 + k0),
                                         (LDS_AS void*)(sB + t * 8), 16, 0, 0);
        __builtin_amdgcn_global_load_lds((const GLOBAL_AS void*)(pb1 + k0),
                                         (LDS_AS void*)(sB + 2048 + t * 8), 16, 0, 0);
        __syncthreads();

        bf16x8 af[4], bv[4];
#pragma unroll
        for (int i = 0; i < 4; ++i)
            af[i] = *reinterpret_cast<const bf16x8*>(sA + aoff + i * 16 * BK);
#pragma unroll
        for (int i = 0; i < 4; ++i)
            bv[i] = *reinterpret_cast<const bf16x8*>(sB + boff + i * 16 * BK);

#pragma unroll
        for (int mi = 0; mi < 4; ++mi)
#pragma unroll
            for (int ni = 0; ni < 4; ++ni)
                acc[mi][ni] = __builtin_amdgcn_mfma_f32_16x16x32_bf16(
                    af[mi], bv[ni], acc[mi][ni], 0, 0, 0);
    }

    // epilogue: C/D layout col = lane&15, row = quad*4 + reg
    float bev[4];
#pragma unroll
    for (int ni = 0; ni < 4; ++ni)
        bev[ni] = be[bn * TN + wc * 64 + ni * 16 + l15];

#pragma unroll
    for (int mi = 0; mi < 4; ++mi) {
        const int grow = bm * TM + wr * 64 + mi * 16 + quad * 4;
#pragma unroll
        for (int ni = 0; ni < 4; ++ni) {
            const int gcol = bn * TN + wc * 64 + ni * 16 + l15;
            float* po = out + (size_t)grow * OUT + gcol;
#pragma unroll
            for (int r = 0; r < 4; ++r)
                po[(size_t)r * OUT] = acc[mi][ni][r] + bev[ni];
        }
    }
}

extern "C" void kernel_launch(void* const* d_in, const int* in_sizes, int n_in,
                              void* d_out, int out_size, void* d_ws, size_t ws_size,
                              hipStream_t stream) {
    const float* x    = (const float*)d_in[0];   // [8192,1024]
    const float* W    = (const float*)d_in[1];   // [1024,1024]
    const float* C    = (const float*)d_in[2];   // [1024,1024,4]
    const float* bias = (const float*)d_in[3];   // [1024]
    float* out = (float*)d_out;

    unsigned short* Ab = (unsigned short*)d_ws;                    // 8192*4096 bf16 = 64 MB
    unsigned short* Bb = Ab + (size_t)BATCH * KDIM;                // 1024*4096 bf16 = 8 MB
    float*          be = (float*)(Bb + (size_t)OUT * KDIM);        // 4 KB

    prep_a<<<dim3(BATCH * IN / 4 / 256), dim3(256), 0, stream>>>(x, Ab);
    prep_b<<<dim3(OUT * IN / 256), dim3(256), 0, stream>>>(W, C, Bb);
    prep_bias<<<dim3(OUT), dim3(256), 0, stream>>>(C, bias, be);

    dim3 grid(OUT / TN, BATCH / TM);   // 8 x 64 = 512 blocks
    gemm_kan<<<grid, dim3(256), 0, stream>>>(Ab, Bb, be, out);
}